// Round 1
// baseline (61388.739 us; speedup 1.0000x reference)
//
#include <hip/hip_runtime.h>
#include <math.h>

// SynchronGRU: 8-layer Keras-v2 GRU (reset_after=True), B=512 T=256 F=8 U=128.
// Each batch row is independent across all layers/timesteps -> blocks own rows,
// no inter-block sync. Activations ping through d_out's front region in-place.
// Thread n<384 holds input-kernel column n in VGPRs; thread 384+n holds the
// recurrent-kernel column n. x_t / h are staged in LDS (broadcast reads).

namespace {

constexpr int kB = 512;
constexpr int kT = 256;
constexpr int kF = 8;
constexpr int kU = 128;
constexpr int kG = 384;   // 3*U, gate order [z, r, h]
constexpr int kL = 8;
constexpr int kRows = 2;  // batch rows per block
constexpr int kThreads = 2 * kG;  // 768 = 12 waves

__global__ __launch_bounds__(kThreads) void gru_all(
    const float* __restrict__ xin,      // (B,T,F)
    const float* __restrict__ init_h,   // (L,B,U)
    const float* __restrict__ kernel0,  // (F,3U)
    const float* __restrict__ kernels,  // (L-1,U,3U)
    const float* __restrict__ rec_k,    // (L,U,3U)
    const float* __restrict__ biases,   // (L,2,3U)
    float* __restrict__ out)            // (B,T,U) seq out | (L,B,U) states
{
    __shared__ __align__(16) float xbuf[kRows][kU];
    __shared__ __align__(16) float hbuf[kRows][kU];
    __shared__ float xacc[kRows][kG];
    __shared__ float hacc[kRows][kG];

    const int tid  = threadIdx.x;
    const int b0   = blockIdx.x * kRows;
    const bool is_x = tid < kG;             // input-projection threads
    const int col  = is_x ? tid : tid - kG; // weight column owned

    const int ru_r = (tid >> 7) & 1;  // valid for tid < 256
    const int ru_u = tid & 127;

    float w[kU];  // fp32 weight column in VGPRs (loops fully unrolled)

    float* __restrict__ buf    = out;                        // in-place activations
    float* __restrict__ states = out + (size_t)kB * kT * kU; // final h per layer

    for (int l = 0; l < kL; ++l) {
        // ---- load this layer's weight column + bias into registers ----
        float bias_reg;
        if (is_x) {
            bias_reg = biases[l * 2 * kG + col];
            if (l == 0) {
#pragma unroll
                for (int k = 0; k < kF; ++k) w[k] = kernel0[k * kG + col];
            } else {
                const float* Wk = kernels + (size_t)(l - 1) * kU * kG + col;
#pragma unroll
                for (int k = 0; k < kU; ++k) w[k] = Wk[(size_t)k * kG];
            }
        } else {
            bias_reg = biases[l * 2 * kG + kG + col];
            const float* Wr = rec_k + (size_t)l * kU * kG + col;
#pragma unroll
            for (int k = 0; k < kU; ++k) w[k] = Wr[(size_t)k * kG];
        }
        // ---- init h ----
        if (tid < kRows * kU) {
            hbuf[ru_r][ru_u] = init_h[(size_t)l * kB * kU + (size_t)(b0 + ru_r) * kU + ru_u];
        }
        __syncthreads();

        for (int t = 0; t < kT; ++t) {
            // ---- stage x_t into LDS ----
            if (l == 0) {
                if (tid < kRows * kF) {
                    const int r = tid >> 3, k = tid & 7;
                    xbuf[r][k] = xin[((size_t)(b0 + r) * kT + t) * kF + k];
                }
            } else {
                if (tid < kRows * kU) {
                    xbuf[ru_r][ru_u] = buf[((size_t)(b0 + ru_r) * kT + t) * kU + ru_u];
                }
            }
            __syncthreads();

            // ---- dot products: x@Wk (threads <384) and h@Wr (threads >=384) ----
            {
                float a0 = bias_reg, a1 = bias_reg;
                if (is_x && l == 0) {
#pragma unroll
                    for (int k = 0; k < kF; ++k) {
                        a0 += xbuf[0][k] * w[k];
                        a1 += xbuf[1][k] * w[k];
                    }
                } else {
                    const float* src0 = is_x ? xbuf[0] : hbuf[0];
                    const float* src1 = is_x ? xbuf[1] : hbuf[1];
                    const float4* v0 = (const float4*)src0;
                    const float4* v1 = (const float4*)src1;
                    float p0 = 0.f, p1 = 0.f;  // second accumulation chains (ILP)
#pragma unroll
                    for (int k4 = 0; k4 < kU / 4; ++k4) {
                        const float4 c0 = v0[k4];
                        const float4 c1 = v1[k4];
                        a0 += c0.x * w[4 * k4 + 0]; p0 += c0.y * w[4 * k4 + 1];
                        a0 += c0.z * w[4 * k4 + 2]; p0 += c0.w * w[4 * k4 + 3];
                        a1 += c1.x * w[4 * k4 + 0]; p1 += c1.y * w[4 * k4 + 1];
                        a1 += c1.z * w[4 * k4 + 2]; p1 += c1.w * w[4 * k4 + 3];
                    }
                    a0 += p0; a1 += p1;
                }
                if (is_x) { xacc[0][col] = a0; xacc[1][col] = a1; }
                else      { hacc[0][col] = a0; hacc[1][col] = a1; }
            }
            __syncthreads();

            // ---- gates + state update (threads 0..255 = (row, unit)) ----
            if (tid < kRows * kU) {
                const int r = ru_r, u = ru_u;
                const float xz = xacc[r][u],          hz = hacc[r][u];
                const float xr = xacc[r][kU + u],     hr = hacc[r][kU + u];
                const float xh = xacc[r][2 * kU + u], hp = hacc[r][2 * kU + u];
                const float z  = 1.f / (1.f + __expf(-(xz + hz)));
                const float rr = 1.f / (1.f + __expf(-(xr + hr)));
                const float hh = tanhf(xh + rr * hp);
                const float h  = z * hbuf[r][u] + (1.f - z) * hh;
                hbuf[r][u] = h;
                buf[((size_t)(b0 + r) * kT + t) * kU + u] = h;  // layer output (in-place)
            }
            __syncthreads();  // hbuf ready for next step's h-dot
        }

        // ---- final state of this layer ----
        if (tid < kRows * kU) {
            states[(size_t)l * kB * kU + (size_t)(b0 + ru_r) * kU + ru_u] = hbuf[ru_r][ru_u];
        }
        __syncthreads();
    }
}

}  // namespace

extern "C" void kernel_launch(void* const* d_in, const int* in_sizes, int n_in,
                              void* d_out, int out_size, void* d_ws, size_t ws_size,
                              hipStream_t stream) {
    const float* xin     = (const float*)d_in[0];
    const float* init_h  = (const float*)d_in[1];
    const float* kernel0 = (const float*)d_in[2];
    const float* kernels = (const float*)d_in[3];
    const float* rec_k   = (const float*)d_in[4];
    const float* biases  = (const float*)d_in[5];
    float* out = (float*)d_out;

    dim3 grid(kB / kRows);   // 256 blocks -> ~1 per CU
    dim3 block(kThreads);    // 768 threads = 12 waves
    gru_all<<<grid, block, 0, stream>>>(xin, init_h, kernel0, kernels, rec_k, biases, out);
}

// Round 2
// 60402.808 us; speedup vs baseline: 1.0163x; 1.0163x over previous
//
#include <hip/hip_runtime.h>
#include <math.h>

// SynchronGRU: 8-layer Keras-v2 GRU (reset_after=True), B=512 T=256 F=8 U=128.
// Persistent-weights design: thread n<384 holds input-kernel column n in VGPRs
// (fp32, 128 regs); thread 384+n holds recurrent-kernel column n. Activations
// broadcast through LDS. Blocks own 2 batch rows each (rows independent).
//
// R1 lesson: without a min-occupancy hint the compiler targeted 2 blocks/CU
// (85 VGPR budget) and spilled w[128] to scratch -> 163 GB HBM traffic, 58 ms.
// __launch_bounds__(768, 3) pins 1 block/CU (12 waves, 3/EU) -> ~170 VGPR
// budget so the weight array is register-resident.

namespace {

constexpr int kB = 512;
constexpr int kT = 256;
constexpr int kF = 8;
constexpr int kU = 128;
constexpr int kG = 384;   // 3*U, gate order [z, r, h]
constexpr int kL = 8;
constexpr int kRows = 2;  // batch rows per block
constexpr int kThreads = 2 * kG;  // 768 = 12 waves

__global__ __launch_bounds__(kThreads, 3) void gru_all(
    const float* __restrict__ xin,      // (B,T,F)
    const float* __restrict__ init_h,   // (L,B,U)
    const float* __restrict__ kernel0,  // (F,3U)
    const float* __restrict__ kernels,  // (L-1,U,3U)
    const float* __restrict__ rec_k,    // (L,U,3U)
    const float* __restrict__ biases,   // (L,2,3U)
    float* __restrict__ out)            // (B,T,U) seq out | (L,B,U) states
{
    __shared__ __align__(16) float xbuf[kRows][kU];
    __shared__ __align__(16) float hbuf[kRows][kU];
    __shared__ float xacc[kRows][kG];
    __shared__ float hacc[kRows][kG];

    const int tid  = threadIdx.x;
    const int b0   = blockIdx.x * kRows;
    const bool is_x = tid < kG;             // input-projection threads
    const int col  = is_x ? tid : tid - kG; // weight column owned

    const int ru_r = (tid >> 7) & 1;  // valid for tid < 256
    const int ru_u = tid & 127;

    float w[kU];  // fp32 weight column — must stay in VGPRs (see launch_bounds)

    float* __restrict__ buf    = out;                        // in-place activations
    float* __restrict__ states = out + (size_t)kB * kT * kU; // final h per layer

    for (int l = 0; l < kL; ++l) {
        // ---- load this layer's weight column + bias into registers ----
        float bias_reg;
        if (is_x) {
            bias_reg = biases[l * 2 * kG + col];
            if (l == 0) {
#pragma unroll
                for (int k = 0; k < kF; ++k) w[k] = kernel0[k * kG + col];
            } else {
                const float* Wk = kernels + (size_t)(l - 1) * kU * kG + col;
#pragma unroll
                for (int k = 0; k < kU; ++k) w[k] = Wk[(size_t)k * kG];
            }
        } else {
            bias_reg = biases[l * 2 * kG + kG + col];
            const float* Wr = rec_k + (size_t)l * kU * kG + col;
#pragma unroll
            for (int k = 0; k < kU; ++k) w[k] = Wr[(size_t)k * kG];
        }
        // ---- init h ----
        if (tid < kRows * kU) {
            hbuf[ru_r][ru_u] = init_h[(size_t)l * kB * kU + (size_t)(b0 + ru_r) * kU + ru_u];
        }
        __syncthreads();

        for (int t = 0; t < kT; ++t) {
            // ---- stage x_t into LDS ----
            if (l == 0) {
                if (tid < kRows * kF) {
                    const int r = tid >> 3, k = tid & 7;
                    xbuf[r][k] = xin[((size_t)(b0 + r) * kT + t) * kF + k];
                }
            } else {
                if (tid < kRows * kU) {
                    xbuf[ru_r][ru_u] = buf[((size_t)(b0 + ru_r) * kT + t) * kU + ru_u];
                }
            }
            __syncthreads();

            // ---- dot products: x@Wk (threads <384) and h@Wr (threads >=384) ----
            {
                float a0 = bias_reg, a1 = bias_reg;
                if (is_x && l == 0) {
#pragma unroll
                    for (int k = 0; k < kF; ++k) {
                        a0 += xbuf[0][k] * w[k];
                        a1 += xbuf[1][k] * w[k];
                    }
                } else {
                    const float* src0 = is_x ? xbuf[0] : hbuf[0];
                    const float* src1 = is_x ? xbuf[1] : hbuf[1];
                    const float4* v0 = (const float4*)src0;
                    const float4* v1 = (const float4*)src1;
                    float p0 = 0.f, p1 = 0.f;  // second accumulation chains (ILP)
#pragma unroll
                    for (int k4 = 0; k4 < kU / 4; ++k4) {
                        const float4 c0 = v0[k4];
                        const float4 c1 = v1[k4];
                        a0 += c0.x * w[4 * k4 + 0]; p0 += c0.y * w[4 * k4 + 1];
                        a0 += c0.z * w[4 * k4 + 2]; p0 += c0.w * w[4 * k4 + 3];
                        a1 += c1.x * w[4 * k4 + 0]; p1 += c1.y * w[4 * k4 + 1];
                        a1 += c1.z * w[4 * k4 + 2]; p1 += c1.w * w[4 * k4 + 3];
                    }
                    a0 += p0; a1 += p1;
                }
                if (is_x) { xacc[0][col] = a0; xacc[1][col] = a1; }
                else      { hacc[0][col] = a0; hacc[1][col] = a1; }
            }
            __syncthreads();

            // ---- gates + state update (threads 0..255 = (row, unit)) ----
            if (tid < kRows * kU) {
                const int r = ru_r, u = ru_u;
                const float xz = xacc[r][u],          hz = hacc[r][u];
                const float xr = xacc[r][kU + u],     hr = hacc[r][kU + u];
                const float xh = xacc[r][2 * kU + u], hp = hacc[r][2 * kU + u];
                const float z  = 1.f / (1.f + __expf(-(xz + hz)));
                const float rr = 1.f / (1.f + __expf(-(xr + hr)));
                const float hh = tanhf(xh + rr * hp);
                const float h  = z * hbuf[r][u] + (1.f - z) * hh;
                hbuf[r][u] = h;
                buf[((size_t)(b0 + r) * kT + t) * kU + u] = h;  // layer output (in-place)
            }
            __syncthreads();  // hbuf ready for next step's h-dot
        }

        // ---- final state of this layer ----
        if (tid < kRows * kU) {
            states[(size_t)l * kB * kU + (size_t)(b0 + ru_r) * kU + ru_u] = hbuf[ru_r][ru_u];
        }
        __syncthreads();
    }
}

}  // namespace

extern "C" void kernel_launch(void* const* d_in, const int* in_sizes, int n_in,
                              void* d_out, int out_size, void* d_ws, size_t ws_size,
                              hipStream_t stream) {
    const float* xin     = (const float*)d_in[0];
    const float* init_h  = (const float*)d_in[1];
    const float* kernel0 = (const float*)d_in[2];
    const float* kernels = (const float*)d_in[3];
    const float* rec_k   = (const float*)d_in[4];
    const float* biases  = (const float*)d_in[5];
    float* out = (float*)d_out;

    dim3 grid(kB / kRows);   // 256 blocks -> 1 per CU
    dim3 block(kThreads);    // 768 threads = 12 waves
    gru_all<<<grid, block, 0, stream>>>(xin, init_h, kernel0, kernels, rec_k, biases, out);
}